// Round 1
// baseline (2244.964 us; speedup 1.0000x reference)
//
#include <hip/hip_runtime.h>
#include <hip/hip_bf16.h>

#define D_MODEL 1024
#define H_HEADS 16
#define HD 64
#define B_BATCH 4
#define N_SEQ 2048
#define BH (B_BATCH*H_HEADS)      // 64
#define M_TOT (B_BATCH*N_SEQ)    // 8192
#define N_QKV (3*D_MODEL)        // 3072

typedef __bf16 bf16x8 __attribute__((ext_vector_type(8)));
typedef float f32x4 __attribute__((ext_vector_type(4)));

__device__ inline ushort f32_to_bf16(float f){
  unsigned u = __float_as_uint(f);
  unsigned r = (u + 0x7fffu + ((u>>16)&1u)) >> 16;
  return (ushort)r;
}
__device__ inline float bf16_to_f32(ushort h){ return __uint_as_float(((unsigned)h)<<16); }

// ---------------- f32 -> bf16 cast ----------------
__global__ void cvt_f32_bf16_kernel(const float* __restrict__ src, ushort* __restrict__ dst, int n){
  int i = (blockIdx.x*blockDim.x + threadIdx.x)*4;
  int stride = gridDim.x*blockDim.x*4;
  for (; i < n; i += stride){
    float4 f = *reinterpret_cast<const float4*>(src+i);
    ushort4 u;
    u.x=f32_to_bf16(f.x); u.y=f32_to_bf16(f.y); u.z=f32_to_bf16(f.z); u.w=f32_to_bf16(f.w);
    *reinterpret_cast<ushort4*>(dst+i) = u;
  }
}

// ---------------- GEMM: C[M][Nc] = A[M][K] * Wt[Nc][K]^T + bias ----------------
// MODE 0: scatter bf16 into qkv [3][BH][N][HD];  MODE 2: f32 out [M][Nc]
// MFMA 16x16x32 bf16 layouts:
//   A-operand: lane l supplies A[row=l&15][k=(l>>4)*8 + j], j=0..7
//   B-operand: lane l supplies B[k=(l>>4)*8 + j][col=l&15]  (= Wt[col][k], row-major friendly)
//   C/D:       lane l reg r holds D[row=(l>>4)*4+r][col=l&15]   [measured: learn_hip m89/m91]
template<int MODE>
__global__ __launch_bounds__(256) void gemm_bt(
    const ushort* __restrict__ A, const ushort* __restrict__ Wt,
    const float* __restrict__ bias, void* __restrict__ out,
    int M, int Ncols, int K)
{
  constexpr int BM=128, BN=128, BK=32;
  __shared__ __align__(16) ushort As[BM][BK+8];
  __shared__ __align__(16) ushort Bs[BN][BK+8];
  const int tid = threadIdx.x;
  const int w = tid>>6, lane = tid&63;
  const int wm = w>>1, wn = w&1;
  const int row0 = blockIdx.y*BM, col0 = blockIdx.x*BN;
  const int lr = lane&15, lk = (lane>>4)*8;
  f32x4 acc[4][4] = {};

  for (int k0=0; k0<K; k0+=BK) {
    __syncthreads();
    #pragma unroll
    for (int i=0;i<2;i++){
      int v = tid + i*256;
      int r = v>>2, c = (v&3)*8;
      *reinterpret_cast<uint4*>(&As[r][c]) = *reinterpret_cast<const uint4*>(&A[(size_t)(row0+r)*K + k0 + c]);
      *reinterpret_cast<uint4*>(&Bs[r][c]) = *reinterpret_cast<const uint4*>(&Wt[(size_t)(col0+r)*K + k0 + c]);
    }
    __syncthreads();
    bf16x8 af[4], bfr[4];
    #pragma unroll
    for (int m=0;m<4;m++)
      af[m] = *reinterpret_cast<const bf16x8*>(&As[wm*64 + m*16 + lr][lk]);
    #pragma unroll
    for (int n=0;n<4;n++)
      bfr[n] = *reinterpret_cast<const bf16x8*>(&Bs[wn*64 + n*16 + lr][lk]);
    #pragma unroll
    for (int m=0;m<4;m++)
      #pragma unroll
      for (int n=0;n<4;n++)
        acc[m][n] = __builtin_amdgcn_mfma_f32_16x16x32_bf16(af[m], bfr[n], acc[m][n], 0,0,0);
  }

  const int orow_base = row0 + wm*64;
  const int ocol_base = col0 + wn*64;
  #pragma unroll
  for (int m=0;m<4;m++){
    #pragma unroll
    for(int n=0;n<4;n++){
      #pragma unroll
      for (int r=0;r<4;r++){
        int gr = orow_base + m*16 + (lane>>4)*4 + r;
        int gc = ocol_base + n*16 + (lane&15);
        float val = acc[m][n][r] + bias[gc];
        if (MODE==0){
          int which = gc >> 10;
          int d = gc & 1023;
          int h = d >> 6, hd = d & 63;
          int b = gr >> 11, nn = gr & 2047;
          ((ushort*)out)[(size_t)which*((size_t)BH*N_SEQ*HD)
                         + ((size_t)(b*H_HEADS + h)*N_SEQ + nn)*HD + hd] = f32_to_bf16(val);
        } else {
          ((float*)out)[(size_t)gr*Ncols + gc] = val;
        }
      }
    }
  }
}

// ---------------- vector flash attention (baseline) ----------------
// 4 waves/block, wave w owns query row blockIdx.x*4+w of head blockIdx.y.
__global__ __launch_bounds__(256) void attn_flash(
    const ushort* __restrict__ q, const ushort* __restrict__ k, const ushort* __restrict__ v,
    ushort* __restrict__ attn_out)
{
  __shared__ unsigned int Ks[64][33];  // 2 bf16 per word, stride 33 words -> conflict-free
  __shared__ float Vs[64][65];         // f32, stride 65 -> conflict-free
  __shared__ float Qs[4][64];
  __shared__ float Ps[4][64];
  const int tid=threadIdx.x, w=tid>>6, lane=tid&63;
  const int bh = blockIdx.y;
  const int row = blockIdx.x*4 + w;
  const size_t base = (size_t)bh * N_SEQ * HD;

  Qs[w][lane] = bf16_to_f32(q[base + (size_t)row*HD + lane]) * 0.125f;  // 1/sqrt(64)
  float o = 0.f, mrun = -1e30f, lrun = 0.f;
  const int maxrow = blockIdx.x*4 + 3;
  const int ntiles = (maxrow >> 6) + 1;

  for (int t=0; t<ntiles; t++){
    const int j0 = t*64;
    __syncthreads();  // previous PV done before restage
    const unsigned int* Ksrc = reinterpret_cast<const unsigned int*>(k + base + (size_t)j0*HD);
    const unsigned int* Vsrc = reinterpret_cast<const unsigned int*>(v + base + (size_t)j0*HD);
    #pragma unroll
    for (int i=0;i<8;i++){
      int idx = tid + i*256;
      int j = idx>>5, c = idx&31;
      Ks[j][c] = Ksrc[j*32 + c];
      unsigned int vw = Vsrc[j*32 + c];
      Vs[j][2*c]   = bf16_to_f32((ushort)(vw & 0xffffu));
      Vs[j][2*c+1] = bf16_to_f32((ushort)(vw >> 16));
    }
    __syncthreads();

    float s = 0.f;
    #pragma unroll
    for (int c=0;c<32;c++){
      unsigned int kw = Ks[lane][c];
      s += Qs[w][2*c]   * bf16_to_f32((ushort)(kw & 0xffffu));
      s += Qs[w][2*c+1] * bf16_to_f32((ushort)(kw >> 16));
    }
    if (j0 + lane > row) s = -1e30f;

    float tmax = s;
    #pragma unroll
    for (int off=1; off<64; off<<=1) tmax = fmaxf(tmax, __shfl_xor(tmax, off));
    float mnew = fmaxf(mrun, tmax);
    float p = __expf(s - mnew);
    float corr = __expf(mrun - mnew);
    float tsum = p;
    #pragma unroll
    for (int off=1; off<64; off<<=1) tsum += __shfl_xor(tsum, off);
    lrun = lrun*corr + tsum;
    mrun = mnew;
    Ps[w][lane] = p;
    o *= corr;
    __syncthreads();  // Ps visible

    #pragma unroll
    for (int j=0;j<64;j++)
      o += Ps[w][j] * Vs[j][lane];
  }
  o /= lrun;
  int b = bh >> 4, h = bh & 15;
  attn_out[((size_t)(b*N_SEQ) + row)*D_MODEL + h*HD + lane] = f32_to_bf16(o);
}

extern "C" void kernel_launch(void* const* d_in, const int* in_sizes, int n_in,
                              void* d_out, int out_size, void* d_ws, size_t ws_size,
                              hipStream_t stream){
  const float* x     = (const float*)d_in[0];
  const float* w_qkv = (const float*)d_in[1];
  const float* b_qkv = (const float*)d_in[2];
  const float* w_out = (const float*)d_in[3];
  const float* b_out = (const float*)d_in[4];

  char* ws = (char*)d_ws;
  size_t off = 0;
  ushort* x_bf    = (ushort*)(ws+off); off += (size_t)M_TOT*D_MODEL*2;
  ushort* wqkv_bf = (ushort*)(ws+off); off += (size_t)N_QKV*D_MODEL*2;
  ushort* wout_bf = (ushort*)(ws+off); off += (size_t)D_MODEL*D_MODEL*2;
  ushort* qkv     = (ushort*)(ws+off); off += 3ull*BH*N_SEQ*HD*2;
  ushort* attn_o  = (ushort*)(ws+off); off += (size_t)M_TOT*D_MODEL*2;

  cvt_f32_bf16_kernel<<<1024, 256, 0, stream>>>(x,     x_bf,    M_TOT*D_MODEL);
  cvt_f32_bf16_kernel<<<512,  256, 0, stream>>>(w_qkv, wqkv_bf, N_QKV*D_MODEL);
  cvt_f32_bf16_kernel<<<256,  256, 0, stream>>>(w_out, wout_bf, D_MODEL*D_MODEL);

  dim3 g1(N_QKV/128, M_TOT/128);
  gemm_bt<0><<<g1, 256, 0, stream>>>(x_bf, wqkv_bf, b_qkv, qkv, M_TOT, N_QKV, D_MODEL);

  const ushort* qb = qkv;
  const ushort* kb = qkv + (size_t)BH*N_SEQ*HD;
  const ushort* vb = kb  + (size_t)BH*N_SEQ*HD;
  dim3 g2(N_SEQ/4, BH);
  attn_flash<<<g2, 256, 0, stream>>>(qb, kb, vb, attn_o);

  dim3 g3(D_MODEL/128, M_TOT/128);
  gemm_bt<2><<<g3, 256, 0, stream>>>(attn_o, wout_bf, b_out, (float*)d_out, M_TOT, D_MODEL, D_MODEL);
}

// Round 2
// 443.338 us; speedup vs baseline: 5.0638x; 5.0638x over previous
//
#include <hip/hip_runtime.h>
#include <hip/hip_bf16.h>

#define D_MODEL 1024
#define H_HEADS 16
#define HD 64
#define B_BATCH 4
#define N_SEQ 2048
#define BH (B_BATCH*H_HEADS)      // 64
#define M_TOT (B_BATCH*N_SEQ)    // 8192
#define N_QKV (3*D_MODEL)        // 3072

typedef __bf16 bf16x8 __attribute__((ext_vector_type(8)));
typedef float f32x4 __attribute__((ext_vector_type(4)));

__device__ inline ushort f32_to_bf16(float f){
  unsigned u = __float_as_uint(f);
  unsigned r = (u + 0x7fffu + ((u>>16)&1u)) >> 16;
  return (ushort)r;
}
__device__ inline float bf16_to_f32(ushort h){ return __uint_as_float(((unsigned)h)<<16); }

#define GLOAD_LDS16(g, l) __builtin_amdgcn_global_load_lds( \
    (const __attribute__((address_space(1))) void*)(g), \
    (__attribute__((address_space(3))) void*)(l), 16, 0, 0)

// ---------------- f32 -> bf16 cast ----------------
__global__ void cvt_f32_bf16_kernel(const float* __restrict__ src, ushort* __restrict__ dst, int n){
  int i = (blockIdx.x*blockDim.x + threadIdx.x)*4;
  int stride = gridDim.x*blockDim.x*4;
  for (; i < n; i += stride){
    float4 f = *reinterpret_cast<const float4*>(src+i);
    ushort4 u;
    u.x=f32_to_bf16(f.x); u.y=f32_to_bf16(f.y); u.z=f32_to_bf16(f.z); u.w=f32_to_bf16(f.w);
    *reinterpret_cast<ushort4*>(dst+i) = u;
  }
}

// ---------------- GEMM: C[M][Nc] = A[M][K] * Wt[Nc][K]^T + bias ----------------
// MODE 0: scatter bf16 into qkv [3][BH][N][HD];  MODE 2: f32 out [M][Nc]
// MFMA 16x16x32 bf16 layouts:
//   A-operand: lane l supplies A[row=l&15][k=(l>>4)*8 + j], j=0..7
//   B-operand: lane l supplies B[k=(l>>4)*8 + j][col=l&15]
//   C/D:       lane l reg r holds D[row=(l>>4)*4+r][col=l&15]
template<int MODE>
__global__ __launch_bounds__(256) void gemm_bt(
    const ushort* __restrict__ A, const ushort* __restrict__ Wt,
    const float* __restrict__ bias, void* __restrict__ out,
    int M, int Ncols, int K)
{
  constexpr int BM=128, BN=128, BK=32;
  __shared__ __align__(16) ushort As[BM][BK];   // linear: global_load_lds dest
  __shared__ __align__(16) ushort Bs[BN][BK];
  const int tid = threadIdx.x;
  const int w = tid>>6, lane = tid&63;
  const int wm = w>>1, wn = w&1;
  const int row0 = blockIdx.y*BM, col0 = blockIdx.x*BN;
  const int lr = lane&15, lko = (lane>>4)*8;
  f32x4 acc[4][4] = {};

  for (int k0=0; k0<K; k0+=BK) {
    __syncthreads();
    // wave w stages rows [(i*4+w)*16, +16) of both tiles; LDS dest = base + lane*16B
    #pragma unroll
    for (int i=0;i<2;i++){
      int rbase = (i*4+w)*16;
      int r = rbase + (lane>>2);
      int c = (lane&3)*8;
      GLOAD_LDS16(&A [(size_t)(row0+r)*K + k0 + c], &As[rbase][0]);
      GLOAD_LDS16(&Wt[(size_t)(col0+r)*K + k0 + c], &Bs[rbase][0]);
    }
    __syncthreads();
    bf16x8 af[4], bfr[4];
    #pragma unroll
    for (int m=0;m<4;m++)
      af[m] = *reinterpret_cast<const bf16x8*>(&As[wm*64 + m*16 + lr][lko]);
    #pragma unroll
    for (int n=0;n<4;n++)
      bfr[n] = *reinterpret_cast<const bf16x8*>(&Bs[wn*64 + n*16 + lr][lko]);
    #pragma unroll
    for (int m=0;m<4;m++)
      #pragma unroll
      for (int n=0;n<4;n++)
        acc[m][n] = __builtin_amdgcn_mfma_f32_16x16x32_bf16(af[m], bfr[n], acc[m][n], 0,0,0);
  }

  const int orow_base = row0 + wm*64;
  const int ocol_base = col0 + wn*64;
  #pragma unroll
  for (int m=0;m<4;m++){
    #pragma unroll
    for(int n=0;n<4;n++){
      #pragma unroll
      for (int r=0;r<4;r++){
        int gr = orow_base + m*16 + (lane>>4)*4 + r;
        int gc = ocol_base + n*16 + (lane&15);
        float val = acc[m][n][r] + bias[gc];
        if (MODE==0){
          int which = gc >> 10;
          int d = gc & 1023;
          int h = d >> 6, hd = d & 63;
          int b = gr >> 11, nn = gr & 2047;
          ((ushort*)out)[(size_t)which*((size_t)BH*N_SEQ*HD)
                         + ((size_t)(b*H_HEADS + h)*N_SEQ + nn)*HD + hd] = f32_to_bf16(val);
        } else {
          ((float*)out)[(size_t)gr*Ncols + gc] = val;
        }
      }
    }
  }
}

// ---------------- MFMA flash attention ----------------
// grid (N_SEQ/64, BH); block 256 = 4 waves. Block owns 64-row Q tile of head bh;
// wave w owns rows [w*16, w*16+16). KV tiles of 64 keys.
__global__ __launch_bounds__(256) void attn_mfma(
    const ushort* __restrict__ q, const ushort* __restrict__ kg, const ushort* __restrict__ vg,
    ushort* __restrict__ attn_out)
{
  constexpr int LS = 72;  // stride: 144B, keeps b128 reads 16B-aligned, bank-uniform
  __shared__ __align__(16) ushort Ks[64][LS];     // K tile row-major [key][dim]
  __shared__ __align__(16) ushort Vt[64][LS];     // V^T [dim][key]
  __shared__ __align__(16) ushort Ps[4][16][LS];  // per-wave P strip [qrow][key]
  const int tid=threadIdx.x, w=tid>>6, lane=tid&63;
  const int lr = lane&15, lk = lane>>4;
  const int bh = blockIdx.y;
  const int row0 = blockIdx.x*64;
  const size_t base = (size_t)bh * N_SEQ * HD;

  // Q fragment (A-operand) straight from global, 2 k-slices
  bf16x8 qf[2];
  #pragma unroll
  for (int ks=0;ks<2;ks++)
    qf[ks] = *reinterpret_cast<const bf16x8*>(&q[base + (size_t)(row0 + w*16 + lr)*HD + ks*32 + lk*8]);

  f32x4 o_acc[4] = {};
  float mrun[4], lrun[4];
  #pragma unroll
  for (int r=0;r<4;r++){ mrun[r]=-1e30f; lrun[r]=0.f; }

  const int ntiles = row0/64 + 1;
  for (int t=0;t<ntiles;t++){
    const int j0 = t*64;
    __syncthreads();   // previous tile's K/V reads done
    #pragma unroll
    for (int i=0;i<2;i++){
      int idx = tid + i*256;
      int r = idx>>3, c = (idx&7)*8;
      *reinterpret_cast<uint4*>(&Ks[r][c]) =
          *reinterpret_cast<const uint4*>(&kg[base + (size_t)(j0+r)*HD + c]);
      uint4 vw = *reinterpret_cast<const uint4*>(&vg[base + (size_t)(j0+r)*HD + c]);
      const ushort* vs = reinterpret_cast<const ushort*>(&vw);
      #pragma unroll
      for (int j=0;j<8;j++) Vt[c+j][r] = vs[j];   // transpose into LDS
    }
    __syncthreads();

    // S = Q K^T  (16x64 strip per wave)
    f32x4 sacc[4] = {};
    #pragma unroll
    for (int ks=0;ks<2;ks++)
      #pragma unroll
      for (int ct=0;ct<4;ct++){
        bf16x8 bf = *reinterpret_cast<const bf16x8*>(&Ks[ct*16+lr][ks*32 + lk*8]);
        sacc[ct] = __builtin_amdgcn_mfma_f32_16x16x32_bf16(qf[ks], bf, sacc[ct], 0,0,0);
      }

    // online softmax; lane owns rows lk*4+r (replicated over 16 lanes of its group)
    float pv[4][4];
    #pragma unroll
    for (int r=0;r<4;r++){
      const int grow = row0 + w*16 + lk*4 + r;
      float mx = -1e30f;
      #pragma unroll
      for (int ct=0;ct<4;ct++){
        float s = sacc[ct][r]*0.125f;                 // 1/sqrt(64)
        if (j0 + ct*16 + lr > grow) s = -1e30f;       // causal mask
        pv[ct][r] = s;
        mx = fmaxf(mx, s);
      }
      #pragma unroll
      for (int off=1; off<16; off<<=1) mx = fmaxf(mx, __shfl_xor(mx, off));
      float mnew = fmaxf(mrun[r], mx);
      float corr = __expf(mrun[r]-mnew);
      float sum = 0.f;
      #pragma unroll
      for (int ct=0;ct<4;ct++){
        float p = __expf(pv[ct][r]-mnew);
        pv[ct][r] = p;
        sum += p;
      }
      #pragma unroll
      for (int off=1; off<16; off<<=1) sum += __shfl_xor(sum, off);
      lrun[r] = lrun[r]*corr + sum;
      mrun[r] = mnew;
      #pragma unroll
      for (int ct=0;ct<4;ct++){
        Ps[w][lk*4+r][ct*16+lr] = f32_to_bf16(pv[ct][r]);
        o_acc[ct][r] *= corr;
      }
    }

    // O += P V   (P via per-wave LDS relayout; V^T gives B-operand reads)
    bf16x8 pa[2];
    #pragma unroll
    for (int ks=0;ks<2;ks++)
      pa[ks] = *reinterpret_cast<const bf16x8*>(&Ps[w][lr][ks*32 + lk*8]);
    #pragma unroll
    for (int ct=0;ct<4;ct++)
      #pragma unroll
      for (int ks=0;ks<2;ks++){
        bf16x8 vb = *reinterpret_cast<const bf16x8*>(&Vt[ct*16+lr][ks*32 + lk*8]);
        o_acc[ct] = __builtin_amdgcn_mfma_f32_16x16x32_bf16(pa[ks], vb, o_acc[ct], 0,0,0);
      }
  }

  const int b = bh>>4, h = bh&15;
  #pragma unroll
  for (int ct=0;ct<4;ct++)
    #pragma unroll
    for (int r=0;r<4;r++){
      int grow = row0 + w*16 + lk*4 + r;
      attn_out[((size_t)(b*N_SEQ) + grow)*D_MODEL + h*HD + ct*16 + lr]
          = f32_to_bf16(o_acc[ct][r] / lrun[r]);
    }
}

extern "C" void kernel_launch(void* const* d_in, const int* in_sizes, int n_in,
                              void* d_out, int out_size, void* d_ws, size_t ws_size,
                              hipStream_t stream){
  const float* x     = (const float*)d_in[0];
  const float* w_qkv = (const float*)d_in[1];
  const float* b_qkv = (const float*)d_in[2];
  const float* w_out = (const float*)d_in[3];
  const float* b_out = (const float*)d_in[4];

  char* ws = (char*)d_ws;
  size_t off = 0;
  ushort* x_bf    = (ushort*)(ws+off); off += (size_t)M_TOT*D_MODEL*2;
  ushort* wqkv_bf = (ushort*)(ws+off); off += (size_t)N_QKV*D_MODEL*2;
  ushort* wout_bf = (ushort*)(ws+off); off += (size_t)D_MODEL*D_MODEL*2;
  ushort* qkv     = (ushort*)(ws+off); off += 3ull*BH*N_SEQ*HD*2;
  ushort* attn_o  = (ushort*)(ws+off); off += (size_t)M_TOT*D_MODEL*2;

  cvt_f32_bf16_kernel<<<1024, 256, 0, stream>>>(x,     x_bf,    M_TOT*D_MODEL);
  cvt_f32_bf16_kernel<<<512,  256, 0, stream>>>(w_qkv, wqkv_bf, N_QKV*D_MODEL);
  cvt_f32_bf16_kernel<<<256,  256, 0, stream>>>(w_out, wout_bf, D_MODEL*D_MODEL);

  dim3 g1(N_QKV/128, M_TOT/128);
  gemm_bt<0><<<g1, 256, 0, stream>>>(x_bf, wqkv_bf, b_qkv, qkv, M_TOT, N_QKV, D_MODEL);

  const ushort* qb = qkv;
  const ushort* kb = qkv + (size_t)BH*N_SEQ*HD;
  const ushort* vb = kb  + (size_t)BH*N_SEQ*HD;
  dim3 g2(N_SEQ/64, BH);
  attn_mfma<<<g2, 256, 0, stream>>>(qb, kb, vb, attn_o);

  dim3 g3(D_MODEL/128, M_TOT/128);
  gemm_bt<2><<<g3, 256, 0, stream>>>(attn_o, wout_bf, b_out, (float*)d_out, M_TOT, D_MODEL, D_MODEL);
}

// Round 3
// 385.876 us; speedup vs baseline: 5.8178x; 1.1489x over previous
//
#include <hip/hip_runtime.h>
#include <hip/hip_bf16.h>

#define D_MODEL 1024
#define H_HEADS 16
#define HD 64
#define B_BATCH 4
#define N_SEQ 2048
#define BH (B_BATCH*H_HEADS)      // 64
#define M_TOT (B_BATCH*N_SEQ)    // 8192
#define N_QKV (3*D_MODEL)        // 3072
#define QSCALE 0.18033688011112042f   // 0.125 * log2(e) folded into q at GEMM epilogue

typedef __bf16 bf16x8 __attribute__((ext_vector_type(8)));
typedef float f32x4 __attribute__((ext_vector_type(4)));

__device__ inline ushort f32_to_bf16(float f){
  unsigned u = __float_as_uint(f);
  unsigned r = (u + 0x7fffu + ((u>>16)&1u)) >> 16;
  return (ushort)r;
}
__device__ inline float bf16_to_f32(ushort h){ return __uint_as_float(((unsigned)h)<<16); }

#define GLOAD_LDS16(g, l) __builtin_amdgcn_global_load_lds( \
    (const __attribute__((address_space(1))) void*)(g), \
    (__attribute__((address_space(3))) void*)(l), 16, 0, 0)

// ---------------- f32 -> bf16 cast ----------------
__global__ void cvt_f32_bf16_kernel(const float* __restrict__ src, ushort* __restrict__ dst, int n){
  int i = (blockIdx.x*blockDim.x + threadIdx.x)*4;
  int stride = gridDim.x*blockDim.x*4;
  for (; i < n; i += stride){
    float4 f = *reinterpret_cast<const float4*>(src+i);
    ushort4 u;
    u.x=f32_to_bf16(f.x); u.y=f32_to_bf16(f.y); u.z=f32_to_bf16(f.z); u.w=f32_to_bf16(f.w);
    *reinterpret_cast<ushort4*>(dst+i) = u;
  }
}

// ---------------- GEMM: C[M][Nc] = A[M][K] * Wt[Nc][K]^T + bias ----------------
// MODE 0: scatter bf16 into q [BH][N][HD] (scaled by QSCALE), k [BH][N][HD], v^T [BH][HD][N]
// MODE 2: f32 out [M][Nc]
template<int MODE>
__global__ __launch_bounds__(256) void gemm_bt(
    const ushort* __restrict__ A, const ushort* __restrict__ Wt,
    const float* __restrict__ bias, void* __restrict__ out,
    int M, int Ncols, int K)
{
  constexpr int BM=128, BN=128, BK=32;
  __shared__ __align__(16) ushort As[BM][BK];   // linear: global_load_lds dest
  __shared__ __align__(16) ushort Bs[BN][BK];
  const int tid = threadIdx.x;
  const int w = tid>>6, lane = tid&63;
  const int wm = w>>1, wn = w&1;
  const int row0 = blockIdx.y*BM, col0 = blockIdx.x*BN;
  const int lr = lane&15, lko = (lane>>4)*8;
  f32x4 acc[4][4] = {};

  for (int k0=0; k0<K; k0+=BK) {
    __syncthreads();
    #pragma unroll
    for (int i=0;i<2;i++){
      int rbase = (i*4+w)*16;
      int r = rbase + (lane>>2);
      int c = (lane&3)*8;
      GLOAD_LDS16(&A [(size_t)(row0+r)*K + k0 + c], &As[rbase][0]);
      GLOAD_LDS16(&Wt[(size_t)(col0+r)*K + k0 + c], &Bs[rbase][0]);
    }
    __syncthreads();
    bf16x8 af[4], bfr[4];
    #pragma unroll
    for (int m=0;m<4;m++)
      af[m] = *reinterpret_cast<const bf16x8*>(&As[wm*64 + m*16 + lr][lko]);
    #pragma unroll
    for (int n=0;n<4;n++)
      bfr[n] = *reinterpret_cast<const bf16x8*>(&Bs[wn*64 + n*16 + lr][lko]);
    #pragma unroll
    for (int m=0;m<4;m++)
      #pragma unroll
      for (int n=0;n<4;n++)
        acc[m][n] = __builtin_amdgcn_mfma_f32_16x16x32_bf16(af[m], bfr[n], acc[m][n], 0,0,0);
  }

  const int orow_base = row0 + wm*64;
  const int ocol_base = col0 + wn*64;
  #pragma unroll
  for (int m=0;m<4;m++){
    #pragma unroll
    for(int n=0;n<4;n++){
      const int gc = ocol_base + n*16 + (lane&15);
      const float bv = bias[gc];
      const int gr0 = orow_base + m*16 + (lane>>4)*4;
      float vals[4];
      #pragma unroll
      for (int r=0;r<4;r++) vals[r] = acc[m][n][r] + bv;
      if (MODE==0){
        const int which = gc >> 10;
        const int d = gc & 1023;
        const int h = d >> 6, hd = d & 63;
        const int b = gr0 >> 11, nn0 = gr0 & 2047;
        ushort* o = (ushort*)out;
        if (which==2){
          // V^T: [BH][HD][N]; rows r are consecutive nn -> pack 4 into one store
          ushort4 u;
          u.x=f32_to_bf16(vals[0]); u.y=f32_to_bf16(vals[1]);
          u.z=f32_to_bf16(vals[2]); u.w=f32_to_bf16(vals[3]);
          *reinterpret_cast<ushort4*>(
            &o[2ull*BH*N_SEQ*HD + ((size_t)(b*H_HEADS+h)*HD + hd)*N_SEQ + nn0]) = u;
        } else {
          const float sc = (which==0) ? QSCALE : 1.0f;
          #pragma unroll
          for (int r=0;r<4;r++)
            o[(size_t)which*((size_t)BH*N_SEQ*HD)
              + ((size_t)(b*H_HEADS+h)*N_SEQ + nn0 + r)*HD + hd] = f32_to_bf16(vals[r]*sc);
        }
      } else {
        #pragma unroll
        for (int r=0;r<4;r++)
          ((float*)out)[(size_t)(gr0+r)*Ncols + gc] = vals[r];
      }
    }
  }
}

// ---------------- MFMA flash attention v2 ----------------
// grid (N_SEQ/128, BH); block 256 = 4 waves; wave w owns q-rows [w*32, w*32+32).
// K [BH][N][HD] row-major; V^T [BH][HD][N]. KV tiles of 64 keys, prefetched.
__global__ __launch_bounds__(256,2) void attn_mfma(
    const ushort* __restrict__ q, const ushort* __restrict__ kg, const ushort* __restrict__ vtg,
    ushort* __restrict__ attn_out)
{
  constexpr int LS = 72;  // 144B row stride: conflict-free b128 reads
  __shared__ __align__(16) ushort Ks[64][LS];     // K tile [key][dim]
  __shared__ __align__(16) ushort Vs[64][LS];     // V^T tile [dim][key]
  __shared__ __align__(16) ushort Ps[4][32][LS];  // per-wave P [qrow][key]
  const int tid=threadIdx.x, w=tid>>6, lane=tid&63;
  const int lr=lane&15, lk=lane>>4;
  const int bh=blockIdx.y;
  const int row0=blockIdx.x*128;
  const int wrow=row0 + w*32;
  const size_t base=(size_t)bh*N_SEQ*HD;

  // Q fragments (A-operand), 2 row-tiles x 2 k-slices
  bf16x8 qf[2][2];
  #pragma unroll
  for (int rt=0;rt<2;rt++)
    #pragma unroll
    for (int ks=0;ks<2;ks++)
      qf[rt][ks] = *reinterpret_cast<const bf16x8*>(
          &q[base + (size_t)(wrow + rt*16 + lr)*HD + ks*32 + lk*8]);

  f32x4 o_acc[2][4] = {};
  float mrun[2][4], lrun[2][4];
  #pragma unroll
  for (int rt=0;rt<2;rt++)
    #pragma unroll
    for (int r=0;r<4;r++){ mrun[rt][r]=-1e30f; lrun[rt][r]=0.f; }

  const int ntiles = row0/64 + 2;
  const int srow = tid>>3;          // 0..31
  const int scol = (tid&7)*8;       // 0..56
  const ushort* kb = kg + base;
  const ushort* vb = vtg + base;    // per-head V^T [HD][N]

  // prologue: load tile 0
  uint4 kr0 = *reinterpret_cast<const uint4*>(&kb[(size_t)(srow)*HD + scol]);
  uint4 kr1 = *reinterpret_cast<const uint4*>(&kb[(size_t)(32+srow)*HD + scol]);
  uint4 vr0 = *reinterpret_cast<const uint4*>(&vb[(size_t)(srow)*N_SEQ + scol]);
  uint4 vr1 = *reinterpret_cast<const uint4*>(&vb[(size_t)(32+srow)*N_SEQ + scol]);

  for (int t=0;t<ntiles;t++){
    const int j0 = t*64;
    __syncthreads();   // previous tile's LDS reads done
    *reinterpret_cast<uint4*>(&Ks[srow][scol])    = kr0;
    *reinterpret_cast<uint4*>(&Ks[32+srow][scol]) = kr1;
    *reinterpret_cast<uint4*>(&Vs[srow][scol])    = vr0;
    *reinterpret_cast<uint4*>(&Vs[32+srow][scol]) = vr1;
    if (t+1 < ntiles){  // prefetch next tile (overlaps compute below)
      const int j1 = j0 + 64;
      kr0 = *reinterpret_cast<const uint4*>(&kb[(size_t)(j1+srow)*HD + scol]);
      kr1 = *reinterpret_cast<const uint4*>(&kb[(size_t)(j1+32+srow)*HD + scol]);
      vr0 = *reinterpret_cast<const uint4*>(&vb[(size_t)(srow)*N_SEQ + j1 + scol]);
      vr1 = *reinterpret_cast<const uint4*>(&vb[(size_t)(32+srow)*N_SEQ + j1 + scol]);
    }
    __syncthreads();   // tile ready

    if (j0 <= wrow + 31){   // else: fully masked for this wave, skip compute
      // S = Q K^T  (32x64 per wave)
      f32x4 sacc[2][4] = {};
      #pragma unroll
      for (int ks=0;ks<2;ks++)
        #pragma unroll
        for (int ct=0;ct<4;ct++){
          bf16x8 kf = *reinterpret_cast<const bf16x8*>(&Ks[ct*16+lr][ks*32+lk*8]);
          sacc[0][ct] = __builtin_amdgcn_mfma_f32_16x16x32_bf16(qf[0][ks], kf, sacc[0][ct], 0,0,0);
          sacc[1][ct] = __builtin_amdgcn_mfma_f32_16x16x32_bf16(qf[1][ks], kf, sacc[1][ct], 0,0,0);
        }

      const bool wmask = (j0 + 63 > wrow);
      #pragma unroll
      for (int rt=0;rt<2;rt++)
        #pragma unroll
        for (int r=0;r<4;r++){
          const int grow = wrow + rt*16 + lk*4 + r;
          if (wmask){
            #pragma unroll
            for (int ct=0;ct<4;ct++)
              if (j0 + ct*16 + lr > grow) sacc[rt][ct][r] = -1e30f;
          }
          float mx = fmaxf(fmaxf(sacc[rt][0][r],sacc[rt][1][r]),
                           fmaxf(sacc[rt][2][r],sacc[rt][3][r]));
          #pragma unroll
          for (int off=1; off<16; off<<=1) mx = fmaxf(mx, __shfl_xor(mx, off));
          const float mnew = fmaxf(mrun[rt][r], mx);
          const float corr = exp2f(mrun[rt][r] - mnew);
          float sum = 0.f;
          #pragma unroll
          for (int ct=0;ct<4;ct++){
            float p = exp2f(sacc[rt][ct][r] - mnew);
            sum += p;
            Ps[w][rt*16 + lk*4 + r][ct*16 + lr] = f32_to_bf16(p);
          }
          #pragma unroll
          for (int off=1; off<16; off<<=1) sum += __shfl_xor(sum, off);
          mrun[rt][r] = mnew;
          lrun[rt][r] = lrun[rt][r]*corr + sum;
          #pragma unroll
          for (int ct=0;ct<4;ct++) o_acc[rt][ct][r] *= corr;
        }

      // O += P V : P from per-wave LDS strip (A-op), V^T rows give B-op
      bf16x8 pa[2][2];
      #pragma unroll
      for (int rt=0;rt<2;rt++)
        #pragma unroll
        for (int ks=0;ks<2;ks++)
          pa[rt][ks] = *reinterpret_cast<const bf16x8*>(&Ps[w][rt*16+lr][ks*32+lk*8]);
      #pragma unroll
      for (int ks=0;ks<2;ks++)
        #pragma unroll
        for (int ct=0;ct<4;ct++){
          bf16x8 vf = *reinterpret_cast<const bf16x8*>(&Vs[ct*16+lr][ks*32+lk*8]);
          o_acc[0][ct] = __builtin_amdgcn_mfma_f32_16x16x32_bf16(pa[0][ks], vf, o_acc[0][ct], 0,0,0);
          o_acc[1][ct] = __builtin_amdgcn_mfma_f32_16x16x32_bf16(pa[1][ks], vf, o_acc[1][ct], 0,0,0);
        }
    }
  }

  const int b = bh>>4, h = bh&15;
  #pragma unroll
  for (int rt=0;rt<2;rt++)
    #pragma unroll
    for (int r=0;r<4;r++){
      const float rinv = 1.0f / lrun[rt][r];
      const int grow = wrow + rt*16 + lk*4 + r;
      #pragma unroll
      for (int ct=0;ct<4;ct++)
        attn_out[((size_t)(b*N_SEQ) + grow)*D_MODEL + h*HD + ct*16 + lr]
            = f32_to_bf16(o_acc[rt][ct][r] * rinv);
    }
}

extern "C" void kernel_launch(void* const* d_in, const int* in_sizes, int n_in,
                              void* d_out, int out_size, void* d_ws, size_t ws_size,
                              hipStream_t stream){
  const float* x     = (const float*)d_in[0];
  const float* w_qkv = (const float*)d_in[1];
  const float* b_qkv = (const float*)d_in[2];
  const float* w_out = (const float*)d_in[3];
  const float* b_out = (const float*)d_in[4];

  char* ws = (char*)d_ws;
  size_t off = 0;
  ushort* x_bf    = (ushort*)(ws+off); off += (size_t)M_TOT*D_MODEL*2;
  ushort* wqkv_bf = (ushort*)(ws+off); off += (size_t)N_QKV*D_MODEL*2;
  ushort* wout_bf = (ushort*)(ws+off); off += (size_t)D_MODEL*D_MODEL*2;
  ushort* qkv     = (ushort*)(ws+off); off += 3ull*BH*N_SEQ*HD*2;
  ushort* attn_o  = (ushort*)(ws+off); off += (size_t)M_TOT*D_MODEL*2;

  cvt_f32_bf16_kernel<<<1024, 256, 0, stream>>>(x,     x_bf,    M_TOT*D_MODEL);
  cvt_f32_bf16_kernel<<<512,  256, 0, stream>>>(w_qkv, wqkv_bf, N_QKV*D_MODEL);
  cvt_f32_bf16_kernel<<<256,  256, 0, stream>>>(w_out, wout_bf, D_MODEL*D_MODEL);

  dim3 g1(N_QKV/128, M_TOT/128);
  gemm_bt<0><<<g1, 256, 0, stream>>>(x_bf, wqkv_bf, b_qkv, qkv, M_TOT, N_QKV, D_MODEL);

  const ushort* qb  = qkv;
  const ushort* kb  = qkv + (size_t)BH*N_SEQ*HD;
  const ushort* vtb = qkv + 2ull*BH*N_SEQ*HD;
  dim3 g2(N_SEQ/128, BH);
  attn_mfma<<<g2, 256, 0, stream>>>(qb, kb, vtb, attn_o);

  dim3 g3(D_MODEL/128, M_TOT/128);
  gemm_bt<2><<<g3, 256, 0, stream>>>(attn_o, wout_bf, b_out, (float*)d_out, M_TOT, D_MODEL, D_MODEL);
}

// Round 4
// 220.050 us; speedup vs baseline: 10.2021x; 1.7536x over previous
//
#include <hip/hip_runtime.h>
#include <hip/hip_bf16.h>

#define D_MODEL 1024
#define H_HEADS 16
#define HD 64
#define B_BATCH 4
#define N_SEQ 2048
#define BH (B_BATCH*H_HEADS)      // 64
#define M_TOT (B_BATCH*N_SEQ)    // 8192
#define N_QKV (3*D_MODEL)        // 3072
#define QSCALE 0.18033688011112042f   // 0.125 * log2(e) folded into q at GEMM epilogue

typedef __bf16 bf16x8 __attribute__((ext_vector_type(8)));
typedef float f32x4 __attribute__((ext_vector_type(4)));

__device__ inline ushort f32_to_bf16(float f){
  unsigned u = __float_as_uint(f);
  unsigned r = (u + 0x7fffu + ((u>>16)&1u)) >> 16;
  return (ushort)r;
}
__device__ inline float bf16_to_f32(ushort h){ return __uint_as_float(((unsigned)h)<<16); }

#define GLOAD_LDS16(g, l) __builtin_amdgcn_global_load_lds( \
    (const __attribute__((address_space(1))) void*)(g), \
    (__attribute__((address_space(3))) void*)(l), 16, 0, 0)

// ---------------- f32 -> bf16 cast ----------------
__global__ void cvt_f32_bf16_kernel(const float* __restrict__ src, ushort* __restrict__ dst, int n){
  int i = (blockIdx.x*blockDim.x + threadIdx.x)*4;
  int stride = gridDim.x*blockDim.x*4;
  for (; i < n; i += stride){
    float4 f = *reinterpret_cast<const float4*>(src+i);
    ushort4 u;
    u.x=f32_to_bf16(f.x); u.y=f32_to_bf16(f.y); u.z=f32_to_bf16(f.z); u.w=f32_to_bf16(f.w);
    *reinterpret_cast<ushort4*>(dst+i) = u;
  }
}

// ---------------- GEMM: C[M][Nc] = A[M][K] * Wt[Nc][K]^T + bias ----------------
// MODE 0: scatter bf16 into q [BH][N][HD] (scaled), k [BH][N][HD], v^T [BH][HD][N]
// MODE 2: f32 out [M][Nc]
template<int MODE>
__global__ __launch_bounds__(256) void gemm_bt(
    const ushort* __restrict__ A, const ushort* __restrict__ Wt,
    const float* __restrict__ bias, void* __restrict__ out,
    int M, int Ncols, int K)
{
  constexpr int BM=128, BN=128, BK=32;
  __shared__ __align__(16) ushort As[BM][BK];
  __shared__ __align__(16) ushort Bs[BN][BK];
  const int tid = threadIdx.x;
  const int w = tid>>6, lane = tid&63;
  const int wm = w>>1, wn = w&1;
  const int row0 = blockIdx.y*BM, col0 = blockIdx.x*BN;
  const int lr = lane&15, lko = (lane>>4)*8;
  f32x4 acc[4][4] = {};

  for (int k0=0; k0<K; k0+=BK) {
    __syncthreads();
    #pragma unroll
    for (int i=0;i<2;i++){
      int rbase = (i*4+w)*16;
      int r = rbase + (lane>>2);
      int c = (lane&3)*8;
      GLOAD_LDS16(&A [(size_t)(row0+r)*K + k0 + c], &As[rbase][0]);
      GLOAD_LDS16(&Wt[(size_t)(col0+r)*K + k0 + c], &Bs[rbase][0]);
    }
    __syncthreads();
    bf16x8 af[4], bfr[4];
    #pragma unroll
    for (int m=0;m<4;m++)
      af[m] = *reinterpret_cast<const bf16x8*>(&As[wm*64 + m*16 + lr][lko]);
    #pragma unroll
    for (int n=0;n<4;n++)
      bfr[n] = *reinterpret_cast<const bf16x8*>(&Bs[wn*64 + n*16 + lr][lko]);
    #pragma unroll
    for (int m=0;m<4;m++)
      #pragma unroll
      for (int n=0;n<4;n++)
        acc[m][n] = __builtin_amdgcn_mfma_f32_16x16x32_bf16(af[m], bfr[n], acc[m][n], 0,0,0);
  }

  const int orow_base = row0 + wm*64;
  const int ocol_base = col0 + wn*64;
  #pragma unroll
  for (int m=0;m<4;m++){
    #pragma unroll
    for(int n=0;n<4;n++){
      const int gc = ocol_base + n*16 + (lane&15);
      const float bv = bias[gc];
      const int gr0 = orow_base + m*16 + (lane>>4)*4;
      float vals[4];
      #pragma unroll
      for (int r=0;r<4;r++) vals[r] = acc[m][n][r] + bv;
      if (MODE==0){
        const int which = gc >> 10;
        const int d = gc & 1023;
        const int h = d >> 6, hd = d & 63;
        const int b = gr0 >> 11, nn0 = gr0 & 2047;
        ushort* o = (ushort*)out;
        if (which==2){
          ushort4 u;
          u.x=f32_to_bf16(vals[0]); u.y=f32_to_bf16(vals[1]);
          u.z=f32_to_bf16(vals[2]); u.w=f32_to_bf16(vals[3]);
          *reinterpret_cast<ushort4*>(
            &o[2ull*BH*N_SEQ*HD + ((size_t)(b*H_HEADS+h)*HD + hd)*N_SEQ + nn0]) = u;
        } else {
          const float sc = (which==0) ? QSCALE : 1.0f;
          #pragma unroll
          for (int r=0;r<4;r++)
            o[(size_t)which*((size_t)BH*N_SEQ*HD)
              + ((size_t)(b*H_HEADS+h)*N_SEQ + nn0 + r)*HD + hd] = f32_to_bf16(vals[r]*sc);
        }
      } else {
        #pragma unroll
        for (int r=0;r<4;r++)
          ((float*)out)[(size_t)(gr0+r)*Ncols + gc] = vals[r];
      }
    }
  }
}

// ---------------- MFMA flash attention v3: swapped QK^T, dbuf gload_lds, paired strips ----
// grid (8, BH); block = 4 waves. Block processes strip bx then strip 15-bx (128 rows each);
// wave w owns q-rows [strip*128 + w*32, +32). KV tiles of 64 keys.
// K [BH][N][HD]; V^T [BH][HD][N]. LDS K/V rows = 128B, source-XOR-swizzled (chunk^=row&7).
__global__ __launch_bounds__(256,2) void attn_mfma(
    const ushort* __restrict__ q, const ushort* __restrict__ kg, const ushort* __restrict__ vtg,
    ushort* __restrict__ attn_out)
{
  __shared__ __align__(16) ushort Ks[2][64][64];
  __shared__ __align__(16) ushort Vs[2][64][64];
  __shared__ __align__(16) ushort Ps[4][32][72];
  const int tid=threadIdx.x, w=tid>>6, lane=tid&63;
  const int lr=lane&15, lk=lane>>4;
  const int bh=blockIdx.y;
  const size_t base=(size_t)bh*N_SEQ*HD;
  const ushort* kb = kg + base;
  const ushort* vb = vtg + base;    // per-head V^T [HD][N]
  const int b = bh>>4, h = bh&15;

  // staging: wave w stages rows [w*16, w*16+16) of K and V^T tiles.
  // lane: row-in-group = lane>>3, slot = lane&7; fetch global chunk slot^row (m173 swizzle)
  const int s_roff = lane>>3;
  const int s_g    = (lane&7) ^ s_roff;     // source chunk index
  // read offsets (ushort units within a 64x64 tile): row kt*16+lr, chunk (ks*4+lk)^(lr&7)
  int rd_base[2];
  #pragma unroll
  for (int ks=0;ks<2;ks++)
    rd_base[ks] = lr*64 + (((ks*4+lk) ^ (lr&7))*8);

  for (int half=0; half<2; half++){
    const int strip = (half==0) ? (int)blockIdx.x : 15 - (int)blockIdx.x;
    const int row0 = strip*128;
    const int wrow = row0 + w*32;
    const int nt = 2*strip + 2;

    bf16x8 qf[2][2];
    #pragma unroll
    for (int qt=0;qt<2;qt++)
      #pragma unroll
      for (int ks=0;ks<2;ks++)
        qf[qt][ks] = *reinterpret_cast<const bf16x8*>(
            &q[base + (size_t)(wrow + qt*16 + lr)*HD + ks*32 + lk*8]);

    f32x4 o_acc[2][4] = {};
    float mrun[2] = {-1e30f,-1e30f}, lrun[2] = {0.f,0.f};

    __syncthreads();   // previous strip's LDS reads done before restaging
    // prologue: stage tile 0 -> buf 0
    {
      const int r0k = w*16, rA = r0k + s_roff;
      GLOAD_LDS16(&kb[(size_t)(rA)*HD + s_g*8],       &Ks[0][r0k][0]);
      GLOAD_LDS16(&kb[(size_t)(rA+8)*HD + s_g*8],     &Ks[0][r0k+8][0]);
      GLOAD_LDS16(&vb[(size_t)(rA)*N_SEQ + s_g*8],    &Vs[0][r0k][0]);
      GLOAD_LDS16(&vb[(size_t)(rA+8)*N_SEQ + s_g*8],  &Vs[0][r0k+8][0]);
    }
    int cur = 0;
    for (int t=0;t<nt;t++){
      __syncthreads();   // drains vmcnt: buf[cur] staged; prior reads of buf[cur^1] done
      if (t+1 < nt){
        const int j1 = (t+1)*64;
        const int r0k = w*16, rA = r0k + s_roff;
        GLOAD_LDS16(&kb[(size_t)(j1+rA)*HD + s_g*8],        &Ks[cur^1][r0k][0]);
        GLOAD_LDS16(&kb[(size_t)(j1+rA+8)*HD + s_g*8],      &Ks[cur^1][r0k+8][0]);
        GLOAD_LDS16(&vb[(size_t)(rA)*N_SEQ + j1 + s_g*8],   &Vs[cur^1][r0k][0]);
        GLOAD_LDS16(&vb[(size_t)(rA+8)*N_SEQ + j1 + s_g*8], &Vs[cur^1][r0k+8][0]);
      }
      const int j0 = t*64;
      if (j0 <= wrow + 31){
        const ushort* Kt = &Ks[cur][0][0];
        const ushort* Vt = &Vs[cur][0][0];
        // S^T = K Q^T : per (qt,kt) lane holds S[k=j0+kt*16+lk*4+r][q=wrow+qt*16+lr]
        f32x4 sacc[2][4] = {};
        #pragma unroll
        for (int ks=0;ks<2;ks++)
          #pragma unroll
          for (int kt=0;kt<4;kt++){
            bf16x8 kf = *reinterpret_cast<const bf16x8*>(Kt + kt*1024 + rd_base[ks]);
            sacc[0][kt] = __builtin_amdgcn_mfma_f32_16x16x32_bf16(kf, qf[0][ks], sacc[0][kt], 0,0,0);
            sacc[1][kt] = __builtin_amdgcn_mfma_f32_16x16x32_bf16(kf, qf[1][ks], sacc[1][kt], 0,0,0);
          }

        const bool tailmask = (j0 + 63 > wrow);
        #pragma unroll
        for (int qt=0;qt<2;qt++){
          const int qrow = wrow + qt*16 + lr;
          if (tailmask){
            #pragma unroll
            for (int kt=0;kt<4;kt++)
              #pragma unroll
              for (int r=0;r<4;r++)
                if (j0 + kt*16 + lk*4 + r > qrow) sacc[qt][kt][r] = -1e30f;
          }
          float mx = -1e30f;
          #pragma unroll
          for (int kt=0;kt<4;kt++)
            #pragma unroll
            for (int r=0;r<4;r++) mx = fmaxf(mx, sacc[qt][kt][r]);
          mx = fmaxf(mx, __shfl_xor(mx, 16));
          mx = fmaxf(mx, __shfl_xor(mx, 32));
          const float mnew = fmaxf(mrun[qt], mx);
          const float corr = exp2f(mrun[qt] - mnew);
          mrun[qt] = mnew;
          float sum = 0.f;
          #pragma unroll
          for (int kt=0;kt<4;kt++){
            float p0 = exp2f(sacc[qt][kt][0]-mnew);
            float p1 = exp2f(sacc[qt][kt][1]-mnew);
            float p2 = exp2f(sacc[qt][kt][2]-mnew);
            float p3 = exp2f(sacc[qt][kt][3]-mnew);
            sum += (p0+p1)+(p2+p3);
            ushort4 pk;
            pk.x=f32_to_bf16(p0); pk.y=f32_to_bf16(p1);
            pk.z=f32_to_bf16(p2); pk.w=f32_to_bf16(p3);
            *reinterpret_cast<ushort4*>(&Ps[w][qt*16+lr][kt*16+lk*4]) = pk;
          }
          sum += __shfl_xor(sum, 16);
          sum += __shfl_xor(sum, 32);
          lrun[qt] = lrun[qt]*corr + sum;
          #pragma unroll
          for (int dt=0;dt<4;dt++) o_acc[qt][dt] *= corr;
        }

        // O^T = V^T P^T : A = V^T rows (Vs), B = P rows read as P^T cols (Ps)
        #pragma unroll
        for (int ks=0;ks<2;ks++){
          bf16x8 pa0 = *reinterpret_cast<const bf16x8*>(&Ps[w][lr][ks*32+lk*8]);
          bf16x8 pa1 = *reinterpret_cast<const bf16x8*>(&Ps[w][16+lr][ks*32+lk*8]);
          #pragma unroll
          for (int dt=0;dt<4;dt++){
            bf16x8 vf = *reinterpret_cast<const bf16x8*>(Vt + dt*1024 + rd_base[ks]);
            o_acc[0][dt] = __builtin_amdgcn_mfma_f32_16x16x32_bf16(vf, pa0, o_acc[0][dt], 0,0,0);
            o_acc[1][dt] = __builtin_amdgcn_mfma_f32_16x16x32_bf16(vf, pa1, o_acc[1][dt], 0,0,0);
          }
        }
      }
      cur ^= 1;
    }

    // epilogue: lane holds O[q=wrow+qt*16+lr][d=dt*16+lk*4+r] -> packed ushort4
    #pragma unroll
    for (int qt=0;qt<2;qt++){
      const float rinv = 1.0f / lrun[qt];
      const size_t rowb = ((size_t)(b*N_SEQ) + wrow + qt*16 + lr)*D_MODEL + h*HD;
      #pragma unroll
      for (int dt=0;dt<4;dt++){
        ushort4 u;
        u.x=f32_to_bf16(o_acc[qt][dt][0]*rinv);
        u.y=f32_to_bf16(o_acc[qt][dt][1]*rinv);
        u.z=f32_to_bf16(o_acc[qt][dt][2]*rinv);
        u.w=f32_to_bf16(o_acc[qt][dt][3]*rinv);
        *reinterpret_cast<ushort4*>(&attn_out[rowb + dt*16 + lk*4]) = u;
      }
    }
  }
}

extern "C" void kernel_launch(void* const* d_in, const int* in_sizes, int n_in,
                              void* d_out, int out_size, void* d_ws, size_t ws_size,
                              hipStream_t stream){
  const float* x     = (const float*)d_in[0];
  const float* w_qkv = (const float*)d_in[1];
  const float* b_qkv = (const float*)d_in[2];
  const float* w_out = (const float*)d_in[3];
  const float* b_out = (const float*)d_in[4];

  char* ws = (char*)d_ws;
  size_t off = 0;
  ushort* x_bf    = (ushort*)(ws+off); off += (size_t)M_TOT*D_MODEL*2;
  ushort* wqkv_bf = (ushort*)(ws+off); off += (size_t)N_QKV*D_MODEL*2;
  ushort* wout_bf = (ushort*)(ws+off); off += (size_t)D_MODEL*D_MODEL*2;
  ushort* qkv     = (ushort*)(ws+off); off += 3ull*BH*N_SEQ*HD*2;
  ushort* attn_o  = (ushort*)(ws+off); off += (size_t)M_TOT*D_MODEL*2;

  cvt_f32_bf16_kernel<<<1024, 256, 0, stream>>>(x,     x_bf,    M_TOT*D_MODEL);
  cvt_f32_bf16_kernel<<<512,  256, 0, stream>>>(w_qkv, wqkv_bf, N_QKV*D_MODEL);
  cvt_f32_bf16_kernel<<<256,  256, 0, stream>>>(w_out, wout_bf, D_MODEL*D_MODEL);

  dim3 g1(N_QKV/128, M_TOT/128);
  gemm_bt<0><<<g1, 256, 0, stream>>>(x_bf, wqkv_bf, b_qkv, qkv, M_TOT, N_QKV, D_MODEL);

  const ushort* qb  = qkv;
  const ushort* kb  = qkv + (size_t)BH*N_SEQ*HD;
  const ushort* vtb = qkv + 2ull*BH*N_SEQ*HD;
  dim3 g2(8, BH);
  attn_mfma<<<g2, 256, 0, stream>>>(qb, kb, vtb, attn_o);

  dim3 g3(D_MODEL/128, M_TOT/128);
  gemm_bt<2><<<g3, 256, 0, stream>>>(attn_o, wout_bf, b_out, (float*)d_out, M_TOT, D_MODEL, D_MODEL);
}

// Round 5
// 191.476 us; speedup vs baseline: 11.7245x; 1.1492x over previous
//
#include <hip/hip_runtime.h>
#include <hip/hip_bf16.h>

#define D_MODEL 1024
#define H_HEADS 16
#define HD 64
#define B_BATCH 4
#define N_SEQ 2048
#define BH (B_BATCH*H_HEADS)      // 64
#define M_TOT (B_BATCH*N_SEQ)    // 8192
#define N_QKV (3*D_MODEL)        // 3072
#define QSCALE 0.18033688011112042f   // 0.125 * log2(e) folded into q at GEMM epilogue

typedef __bf16 bf16x8 __attribute__((ext_vector_type(8)));
typedef __bf16 bf16x4 __attribute__((ext_vector_type(4)));
typedef float f32x4 __attribute__((ext_vector_type(4)));

__device__ inline ushort cvt_bf16(float f){            // compiler-native: fuses to v_cvt_pk_bf16_f32
  return __builtin_bit_cast(ushort, (__bf16)f);
}

#define GLOAD_LDS16(g, l) __builtin_amdgcn_global_load_lds( \
    (const __attribute__((address_space(1))) void*)(g), \
    (__attribute__((address_space(3))) void*)(l), 16, 0, 0)

// ---------------- f32 -> bf16 cast ----------------
__global__ void cvt_f32_bf16_kernel(const float* __restrict__ src, ushort* __restrict__ dst, int n){
  int i = (blockIdx.x*blockDim.x + threadIdx.x)*4;
  int stride = gridDim.x*blockDim.x*4;
  for (; i < n; i += stride){
    float4 f = *reinterpret_cast<const float4*>(src+i);
    ushort4 u;
    u.x=cvt_bf16(f.x); u.y=cvt_bf16(f.y); u.z=cvt_bf16(f.z); u.w=cvt_bf16(f.w);
    *reinterpret_cast<ushort4*>(dst+i) = u;
  }
}

// ---------------- GEMM: C[M][Nc] = A[M][K] * Wt[Nc][K]^T + bias ----------------
// MODE 0: scatter bf16 into q [BH][N][HD] (scaled), k [BH][N][HD], v^T [BH][HD][N]
// MODE 2: f32 out [M][Nc]
template<int MODE>
__global__ __launch_bounds__(256) void gemm_bt(
    const ushort* __restrict__ A, const ushort* __restrict__ Wt,
    const float* __restrict__ bias, void* __restrict__ out,
    int M, int Ncols, int K)
{
  constexpr int BM=128, BN=128, BK=32;
  __shared__ __align__(16) ushort As[BM][BK];
  __shared__ __align__(16) ushort Bs[BN][BK];
  const int tid = threadIdx.x;
  const int w = tid>>6, lane = tid&63;
  const int wm = w>>1, wn = w&1;
  const int row0 = blockIdx.y*BM, col0 = blockIdx.x*BN;
  const int lr = lane&15, lko = (lane>>4)*8;
  f32x4 acc[4][4] = {};

  for (int k0=0; k0<K; k0+=BK) {
    __syncthreads();
    #pragma unroll
    for (int i=0;i<2;i++){
      int rbase = (i*4+w)*16;
      int r = rbase + (lane>>2);
      int c = (lane&3)*8;
      GLOAD_LDS16(&A [(size_t)(row0+r)*K + k0 + c], &As[rbase][0]);
      GLOAD_LDS16(&Wt[(size_t)(col0+r)*K + k0 + c], &Bs[rbase][0]);
    }
    __syncthreads();
    bf16x8 af[4], bfr[4];
    #pragma unroll
    for (int m=0;m<4;m++)
      af[m] = *reinterpret_cast<const bf16x8*>(&As[wm*64 + m*16 + lr][lko]);
    #pragma unroll
    for (int n=0;n<4;n++)
      bfr[n] = *reinterpret_cast<const bf16x8*>(&Bs[wn*64 + n*16 + lr][lko]);
    #pragma unroll
    for (int m=0;m<4;m++)
      #pragma unroll
      for (int n=0;n<4;n++)
        acc[m][n] = __builtin_amdgcn_mfma_f32_16x16x32_bf16(af[m], bfr[n], acc[m][n], 0,0,0);
  }

  const int orow_base = row0 + wm*64;
  const int ocol_base = col0 + wn*64;
  #pragma unroll
  for (int m=0;m<4;m++){
    #pragma unroll
    for(int n=0;n<4;n++){
      const int gc = ocol_base + n*16 + (lane&15);
      const float bv = bias[gc];
      const int gr0 = orow_base + m*16 + (lane>>4)*4;
      float vals[4];
      #pragma unroll
      for (int r=0;r<4;r++) vals[r] = acc[m][n][r] + bv;
      if (MODE==0){
        const int which = gc >> 10;
        const int d = gc & 1023;
        const int h = d >> 6, hd = d & 63;
        const int b = gr0 >> 11, nn0 = gr0 & 2047;
        ushort* o = (ushort*)out;
        if (which==2){
          ushort4 u;
          u.x=cvt_bf16(vals[0]); u.y=cvt_bf16(vals[1]);
          u.z=cvt_bf16(vals[2]); u.w=cvt_bf16(vals[3]);
          *reinterpret_cast<ushort4*>(
            &o[2ull*BH*N_SEQ*HD + ((size_t)(b*H_HEADS+h)*HD + hd)*N_SEQ + nn0]) = u;
        } else {
          const float sc = (which==0) ? QSCALE : 1.0f;
          #pragma unroll
          for (int r=0;r<4;r++)
            o[(size_t)which*((size_t)BH*N_SEQ*HD)
              + ((size_t)(b*H_HEADS+h)*N_SEQ + nn0 + r)*HD + hd] = cvt_bf16(vals[r]*sc);
        }
      } else {
        #pragma unroll
        for (int r=0;r<4;r++)
          ((float*)out)[(size_t)(gr0+r)*Ncols + gc] = vals[r];
      }
    }
  }
}

// ---------------- MFMA flash attention v4 ----------------
// 1D grid 1024: strip = 15 - bid/64 (longest first), bh = bid&63. 3 blocks/CU.
// Block owns 128 q-rows; wave w owns rows [strip*128 + w*32, +32). KV tiles of 64 keys,
// double-buffered via global_load_lds with source-XOR swizzle (m173 pattern).
// Swapped QK^T (S^T = K Q^T) -> lane-local softmax; defer-max (T13, THR=8 log2-units).
__global__ __launch_bounds__(256,3) void attn_mfma(
    const ushort* __restrict__ q, const ushort* __restrict__ kg, const ushort* __restrict__ vtg,
    ushort* __restrict__ attn_out)
{
  __shared__ __align__(16) ushort Ks[2][64][64];
  __shared__ __align__(16) ushort Vs[2][64][64];
  __shared__ __align__(16) ushort Ps[4][32][72];
  const int tid=threadIdx.x, w=tid>>6, lane=tid&63;
  const int lr=lane&15, lk=lane>>4;
  const int bid = blockIdx.x;
  const int strip = 15 - (bid>>6);
  const int bh = bid & 63;
  const size_t base=(size_t)bh*N_SEQ*HD;
  const ushort* kb = kg + base;
  const ushort* vb = vtg + base;    // per-head V^T [HD][N]
  const int b = bh>>4, h = bh&15;

  const int s_roff = lane>>3;
  const int s_g    = (lane&7) ^ s_roff;     // source chunk index (XOR swizzle)
  int rd_base[2];
  #pragma unroll
  for (int ks=0;ks<2;ks++)
    rd_base[ks] = lr*64 + (((ks*4+lk) ^ (lr&7))*8);

  const int row0 = strip*128;
  const int wrow = row0 + w*32;
  const int nt = 2*strip + 2;

  bf16x8 qf[2][2];
  #pragma unroll
  for (int qt=0;qt<2;qt++)
    #pragma unroll
    for (int ks=0;ks<2;ks++)
      qf[qt][ks] = *reinterpret_cast<const bf16x8*>(
          &q[base + (size_t)(wrow + qt*16 + lr)*HD + ks*32 + lk*8]);

  f32x4 o_acc[2][4] = {};
  float mrun[2] = {-1e30f,-1e30f}, lrun[2] = {0.f,0.f};

  // prologue: stage tile 0 -> buf 0
  {
    const int r0k = w*16, rA = r0k + s_roff;
    GLOAD_LDS16(&kb[(size_t)(rA)*HD + s_g*8],       &Ks[0][r0k][0]);
    GLOAD_LDS16(&kb[(size_t)(rA+8)*HD + s_g*8],     &Ks[0][r0k+8][0]);
    GLOAD_LDS16(&vb[(size_t)(rA)*N_SEQ + s_g*8],    &Vs[0][r0k][0]);
    GLOAD_LDS16(&vb[(size_t)(rA+8)*N_SEQ + s_g*8],  &Vs[0][r0k+8][0]);
  }
  int cur = 0;
  for (int t=0;t<nt;t++){
    __syncthreads();   // buf[cur] staged (vmcnt drained); prior reads of buf[cur^1] done
    if (t+1 < nt){
      const int j1 = (t+1)*64;
      const int r0k = w*16, rA = r0k + s_roff;
      GLOAD_LDS16(&kb[(size_t)(j1+rA)*HD + s_g*8],        &Ks[cur^1][r0k][0]);
      GLOAD_LDS16(&kb[(size_t)(j1+rA+8)*HD + s_g*8],      &Ks[cur^1][r0k+8][0]);
      GLOAD_LDS16(&vb[(size_t)(rA)*N_SEQ + j1 + s_g*8],   &Vs[cur^1][r0k][0]);
      GLOAD_LDS16(&vb[(size_t)(rA+8)*N_SEQ + j1 + s_g*8], &Vs[cur^1][r0k+8][0]);
    }
    const int j0 = t*64;
    if (j0 <= wrow + 31){
      const ushort* Kt = &Ks[cur][0][0];
      const ushort* Vt = &Vs[cur][0][0];
      // S^T = K Q^T : lane holds S[k=j0+kt*16+lk*4+r][q=wrow+qt*16+lr]
      f32x4 sacc[2][4] = {};
      __builtin_amdgcn_s_setprio(1);
      #pragma unroll
      for (int ks=0;ks<2;ks++)
        #pragma unroll
        for (int kt=0;kt<4;kt++){
          bf16x8 kf = *reinterpret_cast<const bf16x8*>(Kt + kt*1024 + rd_base[ks]);
          sacc[0][kt] = __builtin_amdgcn_mfma_f32_16x16x32_bf16(kf, qf[0][ks], sacc[0][kt], 0,0,0);
          sacc[1][kt] = __builtin_amdgcn_mfma_f32_16x16x32_bf16(kf, qf[1][ks], sacc[1][kt], 0,0,0);
        }
      __builtin_amdgcn_s_setprio(0);

      const bool tailmask = (j0 + 63 > wrow);
      #pragma unroll
      for (int qt=0;qt<2;qt++){
        const int qrow = wrow + qt*16 + lr;
        if (tailmask){
          #pragma unroll
          for (int kt=0;kt<4;kt++)
            #pragma unroll
            for (int r=0;r<4;r++)
              if (j0 + kt*16 + lk*4 + r > qrow) sacc[qt][kt][r] = -1e30f;
        }
        float mx = -1e30f;
        #pragma unroll
        for (int kt=0;kt<4;kt++)
          #pragma unroll
          for (int r=0;r<4;r++) mx = fmaxf(mx, sacc[qt][kt][r]);
        mx = fmaxf(mx, __shfl_xor(mx, 16));
        mx = fmaxf(mx, __shfl_xor(mx, 32));
        float mcur = mrun[qt];
        if (__any(mx - mcur > 8.0f)){        // defer-max: rescale only when needed
          const float mnew = fmaxf(mcur, mx);
          const float corr = exp2f(mcur - mnew);
          mrun[qt] = mnew; mcur = mnew;
          lrun[qt] *= corr;
          #pragma unroll
          for (int dt=0;dt<4;dt++) o_acc[qt][dt] *= corr;
        }
        float sum = 0.f;
        #pragma unroll
        for (int kt=0;kt<4;kt++){
          float p0 = exp2f(sacc[qt][kt][0]-mcur);
          float p1 = exp2f(sacc[qt][kt][1]-mcur);
          float p2 = exp2f(sacc[qt][kt][2]-mcur);
          float p3 = exp2f(sacc[qt][kt][3]-mcur);
          sum += (p0+p1)+(p2+p3);
          bf16x4 pk;
          pk[0]=(__bf16)p0; pk[1]=(__bf16)p1; pk[2]=(__bf16)p2; pk[3]=(__bf16)p3;
          *reinterpret_cast<bf16x4*>(&Ps[w][qt*16+lr][kt*16+lk*4]) = pk;
        }
        lrun[qt] += sum;                      // per-lane partial; reduced at epilogue
      }

      // O^T = V^T P^T
      #pragma unroll
      for (int ks=0;ks<2;ks++){
        bf16x8 pa0 = *reinterpret_cast<const bf16x8*>(&Ps[w][lr][ks*32+lk*8]);
        bf16x8 pa1 = *reinterpret_cast<const bf16x8*>(&Ps[w][16+lr][ks*32+lk*8]);
        __builtin_amdgcn_s_setprio(1);
        #pragma unroll
        for (int dt=0;dt<4;dt++){
          bf16x8 vf = *reinterpret_cast<const bf16x8*>(Vt + dt*1024 + rd_base[ks]);
          o_acc[0][dt] = __builtin_amdgcn_mfma_f32_16x16x32_bf16(vf, pa0, o_acc[0][dt], 0,0,0);
          o_acc[1][dt] = __builtin_amdgcn_mfma_f32_16x16x32_bf16(vf, pa1, o_acc[1][dt], 0,0,0);
        }
        __builtin_amdgcn_s_setprio(0);
      }
    }
    cur ^= 1;
  }

  // epilogue: reduce lrun across the 4 lane-groups, then packed stores
  #pragma unroll
  for (int qt=0;qt<2;qt++){
    float rl = lrun[qt];
    rl += __shfl_xor(rl, 16);
    rl += __shfl_xor(rl, 32);
    const float rinv = 1.0f / rl;
    const size_t rowb = ((size_t)(b*N_SEQ) + wrow + qt*16 + lr)*D_MODEL + h*HD;
    #pragma unroll
    for (int dt=0;dt<4;dt++){
      bf16x4 u;
      u[0]=(__bf16)(o_acc[qt][dt][0]*rinv);
      u[1]=(__bf16)(o_acc[qt][dt][1]*rinv);
      u[2]=(__bf16)(o_acc[qt][dt][2]*rinv);
      u[3]=(__bf16)(o_acc[qt][dt][3]*rinv);
      *reinterpret_cast<bf16x4*>(&attn_out[rowb + dt*16 + lk*4]) = u;
    }
  }
}

extern "C" void kernel_launch(void* const* d_in, const int* in_sizes, int n_in,
                              void* d_out, int out_size, void* d_ws, size_t ws_size,
                              hipStream_t stream){
  const float* x     = (const float*)d_in[0];
  const float* w_qkv = (const float*)d_in[1];
  const float* b_qkv = (const float*)d_in[2];
  const float* w_out = (const float*)d_in[3];
  const float* b_out = (const float*)d_in[4];

  char* ws = (char*)d_ws;
  size_t off = 0;
  ushort* x_bf    = (ushort*)(ws+off); off += (size_t)M_TOT*D_MODEL*2;
  ushort* wqkv_bf = (ushort*)(ws+off); off += (size_t)N_QKV*D_MODEL*2;
  ushort* wout_bf = (ushort*)(ws+off); off += (size_t)D_MODEL*D_MODEL*2;
  ushort* qkv     = (ushort*)(ws+off); off += 3ull*BH*N_SEQ*HD*2;
  ushort* attn_o  = (ushort*)(ws+off); off += (size_t)M_TOT*D_MODEL*2;

  cvt_f32_bf16_kernel<<<1024, 256, 0, stream>>>(x,     x_bf,    M_TOT*D_MODEL);
  cvt_f32_bf16_kernel<<<512,  256, 0, stream>>>(w_qkv, wqkv_bf, N_QKV*D_MODEL);
  cvt_f32_bf16_kernel<<<256,  256, 0, stream>>>(w_out, wout_bf, D_MODEL*D_MODEL);

  dim3 g1(N_QKV/128, M_TOT/128);
  gemm_bt<0><<<g1, 256, 0, stream>>>(x_bf, wqkv_bf, b_qkv, qkv, M_TOT, N_QKV, D_MODEL);

  const ushort* qb  = qkv;
  const ushort* kb  = qkv + (size_t)BH*N_SEQ*HD;
  const ushort* vtb = qkv + 2ull*BH*N_SEQ*HD;
  attn_mfma<<<1024, 256, 0, stream>>>(qb, kb, vtb, attn_o);

  dim3 g3(D_MODEL/128, M_TOT/128);
  gemm_bt<2><<<g3, 256, 0, stream>>>(attn_o, wout_bf, b_out, (float*)d_out, M_TOT, D_MODEL, D_MODEL);
}